// Round 3
// baseline (110.200 us; speedup 1.0000x reference)
//
#include <hip/hip_runtime.h>
#include <math.h>

#define NQ 14
#define DEPTH 6
#define DIM 16384
#define BLOCK 512
#define NAMP 32
#define STRIDE 34   // float2 slots per row (32 data + 2 pad) = 272 B, 16B-aligned

// RY butterfly: u' = c*u - s*v ; v' = s*u + c*v (componentwise on re/im)
__device__ __forceinline__ void bfly(float2& u, float2& v, float c, float s) {
    float ux = u.x, uy = u.y, vx = v.x, vy = v.y;
    u.x = c * ux - s * vx;  u.y = c * uy - s * vy;
    v.x = s * ux + c * vx;  v.y = s * uy + c * vy;
}

__device__ __forceinline__ float4 pack2(const float2& a, const float2& b) {
    return make_float4(a.x, a.y, b.x, b.y);
}

// Bit convention: qubit q sits at bit position p = 13 - q of the statevector index.
//
// Ownership layouts (which amp bits are register-local per pass):
//   L1: k0..k4 = r          thread: k5..k13  = t0..t8
//   L2: k5..k9 = r          thread: k0..k4 = t0..t4, k10 = t5, k11..k13 = t6..t8
//   L3: k0 = r0, k10..k13 = r1..r4   thread: k1..k6 = t0..t5, k7..k9 = t6..t8
//
// Slot maps (float2 slots):
//   map_A: slot = rowA*34 + colA, colA = k0..k4, rowA = k5..k13
//   map_B: slot = rowB*34 + colB, colB = k5..k9, rowB = k0..k4 | k10<<5 | k11..k13<<6
__global__ __launch_bounds__(BLOCK, 2) void qsim_kernel(
    const float* __restrict__ x,       // (512, 14)
    const float* __restrict__ theta,   // (84,)
    const float* __restrict__ head_w,  // (2, 14)
    const float* __restrict__ head_b,  // (2,)
    float* __restrict__ out)           // (512, 2)
{
    extern __shared__ __align__(16) float2 st[];   // 512*34*8 = 139264 B
    __shared__ float2 gate[DEPTH * 16];            // (c,s) at [d*16 + bitpos]
    __shared__ float redbuf[16];

    const int t = threadIdx.x;
    const int b = blockIdx.x;

    if (t < DEPTH * NQ) {
        int d = t / NQ, q = t - d * NQ;
        float hg = 0.5f * theta[t];
        gate[d * 16 + (13 - q)] = make_float2(cosf(hg), sinf(hg));
    }

    // per-bit-position half-angle trig of the input encoding (qubit q = 13-p)
    float cb[NQ], sb[NQ];
    #pragma unroll
    for (int p = 0; p < NQ; ++p) {
        float h = 0.5f * x[b * NQ + (13 - p)];
        cb[p] = cosf(h); sb[p] = sinf(h);
    }

    // ---- initial state in registers, L1 ownership: k = (t<<5) | r ----
    float Mt = 1.f;
    #pragma unroll
    for (int p = 5; p < 14; ++p) Mt *= ((t >> (p - 5)) & 1) ? sb[p] : cb[p];
    const int pct = __popc(t);
    float2 a[NAMP];
    #pragma unroll
    for (int r = 0; r < NAMP; ++r) {
        float m = Mt;
        #pragma unroll
        for (int p = 0; p < 5; ++p) m *= ((r >> p) & 1) ? sb[p] : cb[p];
        int e = (pct + __popc(r)) & 3;    // (-i)^e
        a[r].x = (e == 0) ? m : ((e == 2) ? -m : 0.f);
        a[r].y = (e == 1) ? -m : ((e == 3) ? m : 0.f);
    }

    // CZ-chain sign mask in L3 ownership: k = r0 | (t<<1) | ((r>>1)<<10)
    uint32_t czm = 0;
    #pragma unroll
    for (int r = 0; r < NAMP; ++r) {
        int k = (r & 1) | (t << 1) | ((r >> 1) << 10);
        czm |= (uint32_t)(__popc(k & (k >> 1)) & 1) << r;
    }

    // ---- per-thread LDS base pointers ----
    float2* const wA = st + t * STRIDE;                                  // T12 write / T31 read
    float2* const rA = st + (t & 0x1E0) * STRIDE + (t & 31);             // T12 read  (+ r*STRIDE)
    float2* const wB = st + t * STRIDE;                                  // T23 write (rowB == t)
    float2* const rB = st + ((t & 15) << 1) * STRIDE + ((t >> 4) & 31);  // T23 read
    float2* const wC = st + ((t >> 4) & 31) * STRIDE + ((t & 15) << 1);  // T31 write

    __syncthreads();   // gate table visible

    #pragma unroll 1
    for (int d = 0; d < DEPTH; ++d) {
        const float2* g = &gate[d * 16];

        // ---- pass 1: bits 0..4 on r0..r4 ----
        #pragma unroll
        for (int p = 0; p < 5; ++p) {
            float2 gg = g[p];
            #pragma unroll
            for (int l = 0; l < NAMP; ++l)
                if (!(l & (1 << p)))
                    bfly(a[l], a[l | (1 << p)], gg.x, gg.y);
        }
        __syncthreads();   // (d>0: T31 map_A reads done; d=0: no-op hazard-wise)

        // T12: write map_A (b128 contiguous), read as L2 (b64)
        {
            float4* w4 = (float4*)wA;
            #pragma unroll
            for (int j = 0; j < 16; ++j) w4[j] = pack2(a[2 * j], a[2 * j + 1]);
        }
        __syncthreads();
        #pragma unroll
        for (int r = 0; r < NAMP; ++r) a[r] = rA[r * STRIDE];

        // ---- pass 2: bits 5..9 on r0..r4 ----
        #pragma unroll
        for (int p = 0; p < 5; ++p) {
            float2 gg = g[5 + p];
            #pragma unroll
            for (int l = 0; l < NAMP; ++l)
                if (!(l & (1 << p)))
                    bfly(a[l], a[l | (1 << p)], gg.x, gg.y);
        }
        __syncthreads();   // map_A reads done before overwrite

        // T23: write map_B (b128 contiguous), read as L3 (b64)
        {
            float4* w4 = (float4*)wB;
            #pragma unroll
            for (int j = 0; j < 16; ++j) w4[j] = pack2(a[2 * j], a[2 * j + 1]);
        }
        __syncthreads();
        #pragma unroll
        for (int r = 0; r < NAMP; ++r)
            a[r] = rB[(r & 1) * STRIDE + (r >> 1) * (32 * STRIDE)];

        // ---- pass 3: bits 10..13 on r1..r4 (r0 spectator) ----
        #pragma unroll
        for (int p = 1; p < 5; ++p) {
            float2 gg = g[9 + p];
            #pragma unroll
            for (int l = 0; l < NAMP; ++l)
                if (!(l & (1 << p)))
                    bfly(a[l], a[l | (1 << p)], gg.x, gg.y);
        }

        if (d < DEPTH - 1) {
            // CZ diagonal via sign-bit XOR (skipped on last layer: probs sign-invariant)
            #pragma unroll
            for (int r = 0; r < NAMP; ++r) {
                uint32_t s = ((czm >> r) & 1u) << 31;
                a[r].x = __uint_as_float(__float_as_uint(a[r].x) ^ s);
                a[r].y = __uint_as_float(__float_as_uint(a[r].y) ^ s);
            }
            __syncthreads();   // map_B reads done before overwrite

            // T31: write map_A (b128 pairs over k0), read canonical L1 (b128)
            #pragma unroll
            for (int j = 0; j < 16; ++j)
                *(float4*)(wC + j * (32 * STRIDE)) = pack2(a[2 * j], a[2 * j + 1]);
            __syncthreads();
            {
                const float4* r4 = (const float4*)wA;
                #pragma unroll
                for (int j = 0; j < 16; ++j) {
                    float4 v = r4[j];
                    a[2 * j]     = make_float2(v.x, v.y);
                    a[2 * j + 1] = make_float2(v.z, v.w);
                }
            }
        }
    }

    // ---- readout from registers (L3 ownership) ----
    // logits[o] = bias[o] + sum_k pr(k) * sum_p hw[o][p]*(1-2*bit_p(k))
    float hw0[NQ], hw1[NQ];
    #pragma unroll
    for (int p = 0; p < NQ; ++p) { hw0[p] = head_w[p]; hw1[p] = head_w[NQ + p]; }
    float b0 = 0.f, b1 = 0.f;
    #pragma unroll
    for (int p = 1; p <= 9; ++p) {   // bits 1..9 from t
        float sg = ((t >> (p - 1)) & 1) ? -1.f : 1.f;
        b0 += sg * hw0[p]; b1 += sg * hw1[p];
    }
    float l0 = 0.f, l1 = 0.f;
    #pragma unroll
    for (int j = 0; j < 16; ++j) {   // j = bits 10..13
        float w0h = b0 + ((j & 1) ? -hw0[10] : hw0[10]) + ((j & 2) ? -hw0[11] : hw0[11])
                       + ((j & 4) ? -hw0[12] : hw0[12]) + ((j & 8) ? -hw0[13] : hw0[13]);
        float w1h = b1 + ((j & 1) ? -hw1[10] : hw1[10]) + ((j & 2) ? -hw1[11] : hw1[11])
                       + ((j & 4) ? -hw1[12] : hw1[12]) + ((j & 8) ? -hw1[13] : hw1[13]);
        float2 a0 = a[2 * j], a1 = a[2 * j + 1];
        float pr0 = a0.x * a0.x + a0.y * a0.y;
        float pr1 = a1.x * a1.x + a1.y * a1.y;
        l0 += pr0 * (w0h + hw0[0]) + pr1 * (w0h - hw0[0]);
        l1 += pr0 * (w1h + hw1[0]) + pr1 * (w1h - hw1[0]);
    }
    #pragma unroll
    for (int off = 32; off > 0; off >>= 1) {
        l0 += __shfl_xor(l0, off);
        l1 += __shfl_xor(l1, off);
    }
    __syncthreads();   // safe reuse of redbuf vs earlier LDS ops
    if ((t & 63) == 0) { redbuf[t >> 6] = l0; redbuf[8 + (t >> 6)] = l1; }
    __syncthreads();
    if (t == 0) {
        float s0 = head_b[0], s1 = head_b[1];
        #pragma unroll
        for (int w = 0; w < 8; ++w) { s0 += redbuf[w]; s1 += redbuf[8 + w]; }
        out[b * 2 + 0] = s0;
        out[b * 2 + 1] = s1;
    }
}

extern "C" void kernel_launch(void* const* d_in, const int* in_sizes, int n_in,
                              void* d_out, int out_size, void* d_ws, size_t ws_size,
                              hipStream_t stream) {
    const float* x      = (const float*)d_in[0];
    const float* theta  = (const float*)d_in[1];
    const float* head_w = (const float*)d_in[2];
    const float* head_b = (const float*)d_in[3];
    float* out = (float*)d_out;
    const int batch = in_sizes[0] / NQ;  // 512
    const size_t lds_bytes = (size_t)BLOCK * STRIDE * sizeof(float2);  // 139264
    qsim_kernel<<<batch, BLOCK, lds_bytes, stream>>>(x, theta, head_w, head_b, out);
}

// Round 4
// 103.082 us; speedup vs baseline: 1.0691x; 1.0691x over previous
//
#include <hip/hip_runtime.h>
#include <math.h>

#define NQ 14
#define DEPTH 6
#define DIM 16384
#define BLOCK 512
#define NAMP 32
#define S 36   // floats per LDS row: 32 data + 4 pad; S%4==0 (b128 align), S%32==4 (bank rotation)

// Real RY butterfly: u' = c*u - s*v ; v' = s*u + c*v
__device__ __forceinline__ void bflyr(float& u, float& v, float c, float s) {
    float uu = u, vv = v;
    u = c * uu - s * vv;
    v = s * uu + c * vv;
}

// Bit convention: qubit q sits at bit position p = 13 - q of the statevector index.
// Each block evolves ONE real component (c=0: re, c=1: im) of one batch item.
//
// Ownership layouts (register-local amp bits per pass):
//   L1: k0..k4 = r         thread: k5..k13 = t0..t8
//   L2: k5..k9 = r         thread: k0..k4 = t0..t4, k10..k13 = t5..t8
//   L3: k0 = r0, k10..k13 = r1..r4   thread: k1..k9 = t0..t8
//
// LDS maps (float slots):
//   map_A: slot = (k>>5)*S + (k&31)                              (T12 w/r, T31 w/r)
//   map_B: row = (k&31)|(((k>>10)&15)<<5), col = (k>>5)&31,
//          slot = row*S + (col ^ (((row>>1)&7)<<2))              (T23 w/r)
__global__ __launch_bounds__(BLOCK, 4) void qsim_kernel(
    const float* __restrict__ x,       // (512, 14)
    const float* __restrict__ theta,   // (84,)
    const float* __restrict__ head_w,  // (2, 14)
    const float* __restrict__ head_b,  // (2,)
    float* __restrict__ out)           // (512, 2), pre-zeroed; accumulated atomically
{
    extern __shared__ __align__(16) float st[];   // 512*36*4 = 73728 B
    __shared__ float2 gate[DEPTH * 16];           // (c,s) at [d*16 + bitpos]
    __shared__ float redbuf[16];

    const int t = threadIdx.x;
    const int b = blockIdx.x >> 1;
    const int c = blockIdx.x & 1;    // 0 = real part, 1 = imaginary part

    if (t < DEPTH * NQ) {
        int d = t / NQ, q = t - d * NQ;
        float hg = 0.5f * theta[t];
        gate[d * 16 + (13 - q)] = make_float2(cosf(hg), sinf(hg));
    }

    // per-bit-position half-angle trig of the input encoding (qubit q = 13-p)
    float cb[NQ], sb[NQ];
    #pragma unroll
    for (int p = 0; p < NQ; ++p) {
        float h = 0.5f * x[b * NQ + (13 - p)];
        cb[p] = cosf(h); sb[p] = sinf(h);
    }

    // ---- initial state (component c) in registers, L1: k = (t<<5) | r ----
    // amp(k) = m(k) * (-i)^popc(k),  m = prod_p (bit_p ? sin : cos)
    // re nonzero iff popc even; im nonzero iff popc odd.
    float Mt = 1.f;
    #pragma unroll
    for (int p = 5; p < 14; ++p) Mt *= ((t >> (p - 5)) & 1) ? sb[p] : cb[p];
    const int pct = __popc(t);
    float a[NAMP];
    #pragma unroll
    for (int r = 0; r < NAMP; ++r) {
        float m = Mt;
        #pragma unroll
        for (int p = 0; p < 5; ++p) m *= ((r >> p) & 1) ? sb[p] : cb[p];
        int e = (pct + __popc(r)) & 3;    // (-i)^e
        a[r] = ((e & 1) == c) ? ((((e >> 1) ^ c) & 1) ? -m : m) : 0.f;
    }

    // CZ-chain sign mask in L3 ownership: k = r0 | (t<<1) | ((r>>1)<<10)
    uint32_t czm = 0;
    #pragma unroll
    for (int r = 0; r < NAMP; ++r) {
        int k = (r & 1) | (t << 1) | ((r >> 1) << 10);
        czm |= (uint32_t)(__popc(k & (k >> 1)) & 1) << r;
    }

    // ---- per-thread LDS pointers ----
    float* const wA = st + t * S;                                   // T12 write / T31 read (b128)
    float* const rA = st + ((t >> 5) << 5) * S + (t & 31);          // T12 read: + r*S      (b32)
    const int xw = (t >> 1) & 7;                                    // T23 write swizzle
    float* const rB = st + ((t & 15) << 1) * S
                         + (((t >> 4) & 31) ^ ((t & 7) << 2));      // T23 read: +(r&1)*S + (r>>1)*32*S
    float* const wC = st + (t >> 4) * S + ((t & 15) << 1);          // T31 write: + (r>>1)*32*S (b64)

    __syncthreads();   // gate table visible

    #pragma unroll 1
    for (int d = 0; d < DEPTH; ++d) {
        const float2* g = &gate[d * 16];

        // ---- pass 1: bits 0..4 on r0..r4 ----
        #pragma unroll
        for (int p = 0; p < 5; ++p) {
            float2 gg = g[p];
            #pragma unroll
            for (int l = 0; l < NAMP; ++l)
                if (!(l & (1 << p)))
                    bflyr(a[l], a[l | (1 << p)], gg.x, gg.y);
        }
        __syncthreads();   // prior map_A readers (T31 read / none at d=0) done

        // T12: write map_A (b128, conflict-free), read as L2 (b32, 2-way free)
        #pragma unroll
        for (int j = 0; j < 8; ++j)
            *(float4*)(wA + 4 * j) = make_float4(a[4*j], a[4*j+1], a[4*j+2], a[4*j+3]);
        __syncthreads();
        #pragma unroll
        for (int r = 0; r < NAMP; ++r) a[r] = rA[r * S];

        // ---- pass 2: bits 5..9 on r0..r4 ----
        #pragma unroll
        for (int p = 0; p < 5; ++p) {
            float2 gg = g[5 + p];
            #pragma unroll
            for (int l = 0; l < NAMP; ++l)
                if (!(l & (1 << p)))
                    bflyr(a[l], a[l | (1 << p)], gg.x, gg.y);
        }
        __syncthreads();   // map_A reads done before map_B overwrite

        // T23: write map_B (b128 swizzled, conflict-free), read as L3 (b32, 2-way free)
        #pragma unroll
        for (int gp = 0; gp < 8; ++gp)
            *(float4*)(wA + ((gp ^ xw) << 2)) = make_float4(a[4*gp], a[4*gp+1], a[4*gp+2], a[4*gp+3]);
        __syncthreads();
        #pragma unroll
        for (int r = 0; r < NAMP; ++r)
            a[r] = rB[(r & 1) * S + (r >> 1) * (32 * S)];

        // ---- pass 3: bits 10..13 on r1..r4 (r0 spectator) ----
        #pragma unroll
        for (int p = 1; p < 5; ++p) {
            float2 gg = g[9 + p];
            #pragma unroll
            for (int l = 0; l < NAMP; ++l)
                if (!(l & (1 << p)))
                    bflyr(a[l], a[l | (1 << p)], gg.x, gg.y);
        }

        if (d < DEPTH - 1) {
            // CZ diagonal via sign-bit XOR (skipped on last layer: probs sign-invariant)
            #pragma unroll
            for (int r = 0; r < NAMP; ++r) {
                uint32_t sg = ((czm >> r) & 1u) << 31;
                a[r] = __uint_as_float(__float_as_uint(a[r]) ^ sg);
            }
            __syncthreads();   // map_B reads done before map_A overwrite

            // T31: write map_A (b64 pairs over k0, conflict-free), read as L1 (b128)
            #pragma unroll
            for (int j = 0; j < 16; ++j)
                *(float2*)(wC + j * (32 * S)) = make_float2(a[2*j], a[2*j+1]);
            __syncthreads();
            #pragma unroll
            for (int j = 0; j < 8; ++j) {
                float4 v = *(const float4*)(wA + 4 * j);
                a[4*j] = v.x; a[4*j+1] = v.y; a[4*j+2] = v.z; a[4*j+3] = v.w;
            }
        }
    }

    // ---- readout from registers (L3 ownership): partial logits for this component ----
    // logit[o] += sum_k comp(k)^2 * sum_p hw[o][p]*(1-2*bit_p(k))
    float hw0[NQ], hw1[NQ];
    #pragma unroll
    for (int p = 0; p < NQ; ++p) { hw0[p] = head_w[p]; hw1[p] = head_w[NQ + p]; }
    float b0 = 0.f, b1 = 0.f;
    #pragma unroll
    for (int p = 1; p <= 9; ++p) {   // bits 1..9 from t
        float sg = ((t >> (p - 1)) & 1) ? -1.f : 1.f;
        b0 += sg * hw0[p]; b1 += sg * hw1[p];
    }
    float l0 = 0.f, l1 = 0.f;
    #pragma unroll
    for (int j = 0; j < 16; ++j) {   // j = bits 10..13
        float w0h = b0 + ((j & 1) ? -hw0[10] : hw0[10]) + ((j & 2) ? -hw0[11] : hw0[11])
                       + ((j & 4) ? -hw0[12] : hw0[12]) + ((j & 8) ? -hw0[13] : hw0[13]);
        float w1h = b1 + ((j & 1) ? -hw1[10] : hw1[10]) + ((j & 2) ? -hw1[11] : hw1[11])
                       + ((j & 4) ? -hw1[12] : hw1[12]) + ((j & 8) ? -hw1[13] : hw1[13]);
        float pr0 = a[2*j] * a[2*j];
        float pr1 = a[2*j+1] * a[2*j+1];
        l0 += pr0 * (w0h + hw0[0]) + pr1 * (w0h - hw0[0]);
        l1 += pr0 * (w1h + hw1[0]) + pr1 * (w1h - hw1[0]);
    }
    #pragma unroll
    for (int off = 32; off > 0; off >>= 1) {
        l0 += __shfl_xor(l0, off);
        l1 += __shfl_xor(l1, off);
    }
    if ((t & 63) == 0) { redbuf[t >> 6] = l0; redbuf[8 + (t >> 6)] = l1; }
    __syncthreads();
    if (t == 0) {
        float s0 = 0.f, s1 = 0.f;
        #pragma unroll
        for (int w = 0; w < 8; ++w) { s0 += redbuf[w]; s1 += redbuf[8 + w]; }
        if (c == 0) { s0 += head_b[0]; s1 += head_b[1]; }  // bias added once per item
        atomicAdd(&out[b * 2 + 0], s0);
        atomicAdd(&out[b * 2 + 1], s1);
    }
}

extern "C" void kernel_launch(void* const* d_in, const int* in_sizes, int n_in,
                              void* d_out, int out_size, void* d_ws, size_t ws_size,
                              hipStream_t stream) {
    const float* x      = (const float*)d_in[0];
    const float* theta  = (const float*)d_in[1];
    const float* head_w = (const float*)d_in[2];
    const float* head_b = (const float*)d_in[3];
    float* out = (float*)d_out;
    const int batch = in_sizes[0] / NQ;  // 512
    hipMemsetAsync(out, 0, (size_t)out_size * sizeof(float), stream);
    const size_t lds_bytes = (size_t)BLOCK * S * sizeof(float);  // 73728
    qsim_kernel<<<batch * 2, BLOCK, lds_bytes, stream>>>(x, theta, head_w, head_b, out);
}

// Round 5
// 80.698 us; speedup vs baseline: 1.3656x; 1.2774x over previous
//
#include <hip/hip_runtime.h>
#include <math.h>

#define NQ 14
#define DEPTH 6
#define BLOCK 1024

typedef _Float16 h16;
typedef h16 h8 __attribute__((ext_vector_type(8)));
typedef float f4 __attribute__((ext_vector_type(4)));

template<int N> struct IC { static constexpr int value = N; };

// 14-qubit statevector sim on the matrix pipe. Bit b = 13 - qubit; comp (re/im)
// is "bit 14" (gates are real -> re/im never mix; identity on comp).
// Groups: g0=[0..3] g1=[4..7] g2=[8..11] g3=[12,13,comp,4] (identity on comp,b4).
// Pass p applies the 16x16 matrix of group g_p via mfma_f32_16x16x32_f16
// (K zero-padded to 32); in-tile rows = g_{p+1} so each lane's 4 C-outputs are
// f16-contiguous (b64 write) and next pass's A-read is b128-contiguous.
// CZ chain: intra-group pairs baked into next layer's B matrices; cross pairs
// (3,4),(7,8),(11,12) = per-lane B sign flip at passes 0,1,2 ((lane&1)&&kg==1).
// XOR swizzle (f16 addr bits 4,5 ^= new-group bits 0,1) on both write and read
// makes all LDS traffic bank-conflict-free. Two 64KB f16 buffers ping-pong.

__global__ __launch_bounds__(BLOCK, 4) void qsim_kernel(
    const float* __restrict__ x, const float* __restrict__ theta,
    const float* __restrict__ head_w, const float* __restrict__ head_b,
    float* __restrict__ out)
{
  extern __shared__ __align__(16) char sbuf[];   // 2 x 65536 B state buffers
  __shared__ __align__(16) h16 Bm[24][256];      // B[n*16+k] = M[n][k] per (d,p)
  __shared__ float2 gtab[DEPTH * NQ];            // (cos,sin) theta/2 at [d*14+bit]
  __shared__ float wT7[2][128];                  // head weights over bits 5..11
  __shared__ float wRN[2][2][16];                // [o][0]: bits 0-3; [o][1]: b12,b13,b4
  __shared__ float xc[NQ], xs[NQ];               // input-encoding trig per bit
  __shared__ float redbuf[32];

  const int t = threadIdx.x;
  const int b = blockIdx.x;
  const int lane = t & 63;
  const int w = t >> 6;
  const int m = lane & 15;     // A row / B col / C col
  const int kg = lane >> 4;    // k-group

  // ---- phase 0: small tables ----
  if (t < DEPTH * NQ) {
    int d = t / NQ, bit = t - d * NQ;
    float hg = 0.5f * theta[d * NQ + (13 - bit)];
    gtab[t] = make_float2(cosf(hg), sinf(hg));
  } else if (t >= 128 && t < 384) {
    int o = (t - 128) >> 7, v = (t - 128) & 127;
    float s = 0.f;
    #pragma unroll
    for (int i = 0; i < 7; ++i)
      s += ((v >> i) & 1) ? -head_w[o * NQ + 5 + i] : head_w[o * NQ + 5 + i];
    wT7[o][v] = s;
  } else if (t >= 384 && t < 448) {
    int u = t - 384, o = u >> 5, half = (u >> 4) & 1, idx = u & 15;
    float s;
    if (half == 0) {
      s = 0.f;
      #pragma unroll
      for (int i = 0; i < 4; ++i)
        s += ((idx >> i) & 1) ? -head_w[o * NQ + i] : head_w[o * NQ + i];
    } else {
      s  = (idx & 1) ? -head_w[o * NQ + 12] : head_w[o * NQ + 12];
      s += (idx & 2) ? -head_w[o * NQ + 13] : head_w[o * NQ + 13];
      s += (idx & 8) ? -head_w[o * NQ + 4]  : head_w[o * NQ + 4];
      // idx bit 2 = comp: no weight
    }
    wRN[o][half][idx] = s;
  } else if (t >= 448 && t < 448 + NQ) {
    int bit = t - 448;
    float h = 0.5f * x[b * NQ + (13 - bit)];
    xc[bit] = cosf(h); xs[bit] = sinf(h);
  }
  __syncthreads();

  // ---- phase 1a: B matrices (16x16 group transforms, CZ-intra pre-scaled) ----
  #pragma unroll
  for (int i = 0; i < 6; ++i) {
    int e = t + (i << 10);
    int pid = e >> 8, n = (e >> 4) & 15, k = e & 15;
    int d = pid >> 2, p = pid & 3;
    float val;
    if (p < 3) {
      val = 1.f;
      #pragma unroll
      for (int j = 0; j < 4; ++j) {
        float2 g = gtab[d * NQ + 4 * p + j];
        val *= ((n >> j) & 1) ? (((k >> j) & 1) ? g.x : g.y)
                              : (((k >> j) & 1) ? -g.y : g.x);
      }
      if (d >= 1) {  // CZ(d-1) intra pairs (4p,4p+1),(4p+1,4p+2),(4p+2,4p+3)
        int s = ((k & (k >> 1)) ^ ((k >> 1) & (k >> 2)) ^ ((k >> 2) & (k >> 3))) & 1;
        if (s) val = -val;
      }
    } else {       // g3 = [12,13,comp,4]: G12 x G13 x I x I
      if ((((n ^ k) >> 2) & 3) != 0) val = 0.f;
      else {
        float2 gA = gtab[d * NQ + 12], gB = gtab[d * NQ + 13];
        float f0 = (n & 1) ? ((k & 1) ? gA.x : gA.y) : ((k & 1) ? -gA.y : gA.x);
        float f1 = ((n >> 1) & 1) ? (((k >> 1) & 1) ? gB.x : gB.y)
                                  : (((k >> 1) & 1) ? -gB.y : gB.x);
        val = f0 * f1;
        if (d >= 1 && (k & (k >> 1) & 1)) val = -val;   // pair (12,13)
      }
    }
    Bm[pid][n * 16 + k] = (h16)val;
  }

  // ---- phase 1b: initial product state -> buf0 (view-0 layout, f16) ----
  {
    int comp = t >> 9;
    int khi = t & 511;                       // k bits 5..13
    float mhi = 1.f;
    #pragma unroll
    for (int p2 = 5; p2 < 14; ++p2)
      mhi *= ((khi >> (p2 - 5)) & 1) ? xs[p2] : xc[p2];
    int pchi = __popc(khi);
    uint32_t base = ((uint32_t)khi << 6) + ((uint32_t)comp << 15);
    uint32_t swzb = (((uint32_t)khi >> 7) & 3) << 5;   // k bits 12,13
    #pragma unroll
    for (int blk = 0; blk < 4; ++blk) {
      union { h16 h[8]; uint4 u; } pk;
      #pragma unroll
      for (int i = 0; i < 8; ++i) {
        int j = blk * 8 + i;
        float mm = mhi;
        #pragma unroll
        for (int p2 = 0; p2 < 5; ++p2)
          mm *= ((j >> p2) & 1) ? xs[p2] : xc[p2];
        int e = (pchi + __popc(j)) & 3;       // (-i)^e
        float v = (comp == 0) ? ((e == 0) ? mm : ((e == 2) ? -mm : 0.f))
                              : ((e == 1) ? -mm : ((e == 3) ? mm : 0.f));
        pk.h[i] = (h16)v;
      }
      *(uint4*)(sbuf + ((base + blk * 16) ^ swzb)) = pk.u;
    }
  }
  __syncthreads();

  char* buf0 = sbuf;
  char* buf1 = sbuf + 65536;
  float l0 = 0.f, l1 = 0.f;

  auto pass = [&](auto pc, const char* src, char* dst, int d, bool last) {
    constexpr int P = decltype(pc)::value;
    // B fragment: B[k][n] at k=kg*8+i, n=m  (upper K half zero)
    const h16* Bp = &Bm[d * 4 + P][0];
    h8 bv = {};
    if (kg < 2) bv = *(const h8*)(Bp + (m << 4) + (kg << 3));
    if (d >= 1 && P < 3 && (lane & 1) && kg == 1) {   // CZ cross pair sign
      union { h8 v; uint4 u; } f; f.v = bv;
      f.u.x ^= 0x80008000u; f.u.y ^= 0x80008000u;
      f.u.z ^= 0x80008000u; f.u.w ^= 0x80008000u;
      bv = f.v;
    }
    const int n = m;
    // A-read base: (T<<9) + (m<<5) + (kg<<4), T = w*8+jt; plus view-p swizzle
    uint32_t abase = ((uint32_t)w << 12) + ((uint32_t)m << 5) + ((uint32_t)kg << 4);
    if constexpr (P == 0) abase ^= (((uint32_t)(w >> 1) & 3) << 5);
    if constexpr (P == 2) abase ^= ((((uint32_t)(lane >> 3) & 1)
                                   | (((uint32_t)(w >> 1) & 1) << 1)) << 5);
    if constexpr (P == 3) abase ^= (((uint32_t)w & 3) << 5);
    // C-write base (pre-XOR) and per-tile step, into view p+1
    uint32_t wb, wstep;
    const uint32_t wxor = ((uint32_t)n & 3) << 5;
    if constexpr (P == 0) {
      wb = ((uint32_t)kg << 3) + (((uint32_t)w & 1) << 8) + ((uint32_t)n << 9)
         + (((uint32_t)w >> 1) << 13);
      wstep = 32;
    } else if constexpr (P == 1) {
      uint32_t up = (((uint32_t)w >> 1) & 7) | (((uint32_t)n & 1) << 3);
      wb = ((uint32_t)kg << 3) + (up << 5) + (((uint32_t)w & 1) << 12)
         + (((uint32_t)n >> 1) << 13);
      wstep = 512;
    } else if constexpr (P == 2) {
      uint32_t tp = (((uint32_t)w >> 1) & 7) | ((uint32_t)n << 3);
      wb = ((uint32_t)kg << 3) + (((uint32_t)w & 1) << 8) + (tp << 9);
      wstep = 32;
    } else {
      uint32_t tp = (uint32_t)w | (((uint32_t)n & 7) << 4);
      wb = ((uint32_t)kg << 3) + (((uint32_t)n >> 3) << 5) + (tp << 9);
      wstep = 64;
    }
    float wn0 = 0.f, wn1 = 0.f;
    if (last) { wn0 = wRN[0][1][m]; wn1 = wRN[1][1][m]; }
    #pragma unroll
    for (int jt = 0; jt < 8; ++jt) {
      uint32_t ra = abase + ((uint32_t)jt << 9);
      if constexpr (P == 1) ra ^= ((uint32_t)jt & 3) << 5;
      h8 av = {};
      if (kg < 2) av = *(const h8*)(src + ra);
      f4 acc = {0.f, 0.f, 0.f, 0.f};
      acc = __builtin_amdgcn_mfma_f32_16x16x32_f16(av, bv, acc, 0, 0, 0);
      if (!last) {
        union { h16 h[4]; uint2 u; } pk;
        pk.h[0] = (h16)acc[0]; pk.h[1] = (h16)acc[1];
        pk.h[2] = (h16)acc[2]; pk.h[3] = (h16)acc[3];
        *(uint2*)(dst + ((wb + (uint32_t)jt * wstep) ^ wxor)) = pk.u;
      } else {
        // readout: value coords: rows'=g0 val (kg*4+j), n=g3 val, T=bits 5..11
        int T = w * 8 + jt;
        float wt0 = wT7[0][T], wt1 = wT7[1][T];
        #pragma unroll
        for (int j = 0; j < 4; ++j) {
          float pr = acc[j] * acc[j];
          int rp = kg * 4 + j;
          l0 += pr * (wt0 + wRN[0][0][rp] + wn0);
          l1 += pr * (wt1 + wRN[1][0][rp] + wn1);
        }
      }
    }
  };

  for (int d = 0; d < DEPTH; ++d) {
    pass(IC<0>{}, buf0, buf1, d, false); __syncthreads();
    pass(IC<1>{}, buf1, buf0, d, false); __syncthreads();
    pass(IC<2>{}, buf0, buf1, d, false); __syncthreads();
    bool last = (d == DEPTH - 1);
    pass(IC<3>{}, buf1, buf0, d, last);
    if (!last) __syncthreads();
  }

  #pragma unroll
  for (int off = 32; off > 0; off >>= 1) {
    l0 += __shfl_xor(l0, off);
    l1 += __shfl_xor(l1, off);
  }
  if (lane == 0) { redbuf[w] = l0; redbuf[16 + w] = l1; }
  __syncthreads();
  if (t == 0) {
    float s0 = head_b[0], s1 = head_b[1];
    #pragma unroll
    for (int i = 0; i < 16; ++i) { s0 += redbuf[i]; s1 += redbuf[16 + i]; }
    out[b * 2 + 0] = s0;
    out[b * 2 + 1] = s1;
  }
}

extern "C" void kernel_launch(void* const* d_in, const int* in_sizes, int n_in,
                              void* d_out, int out_size, void* d_ws, size_t ws_size,
                              hipStream_t stream) {
    const float* x      = (const float*)d_in[0];
    const float* theta  = (const float*)d_in[1];
    const float* head_w = (const float*)d_in[2];
    const float* head_b = (const float*)d_in[3];
    float* outp = (float*)d_out;
    const int batch = in_sizes[0] / NQ;  // 512
    qsim_kernel<<<batch, BLOCK, 131072, stream>>>(x, theta, head_w, head_b, outp);
}

// Round 6
// 79.942 us; speedup vs baseline: 1.3785x; 1.0095x over previous
//
#include <hip/hip_runtime.h>
#include <math.h>

#define NQ 14
#define DEPTH 6
#define BLOCK 1024
#define TS 544u   // bytes per T-tile: 512 data + 32 pad; TS/4 % 32 == 4 -> bank rotation 8/tile

typedef _Float16 h16;
typedef h16 h8 __attribute__((ext_vector_type(8)));
typedef float f4 __attribute__((ext_vector_type(4)));

template<int N> struct IC { static constexpr int value = N; };

// 14-qubit statevector sim on the matrix pipe. Bit b = 13 - qubit; comp (re/im)
// is "bit 14" (gates are real). Groups: g0=[0..3] g1=[4..7] g2=[8..11]
// g3=[12,13,comp,4]. Pass p applies group g_p's 16x16 via mfma_f32_16x16x32_f16.
// View p layout (bytes): T*544 + R*32 + G*2, G = g_p value, R = g_{p+1} value,
// T = 7-bit enum E_p of the rest:
//   E0=[12,13,c,8,9,10,11] E1=[0,1,2,3,12,13,c] E2=[5,6,7,0,1,2,3] E3=[8,9,10,11,5,6,7]
// Reads: lane(kg<2,m): T*544 + m*32 + kg*16 (b128). Writes: lane(kg,m) holds 4
// C-values at R-coord kg*4+j, new-G m -> b64 at T''*544 + R''*32 + kg*8 with
// T'' low bits = m. With the 544 stride every access meets the bank minimum
// (verified per-pattern); no XOR swizzles anywhere.

__global__ __launch_bounds__(BLOCK, 4) void qsim_kernel(
    const float* __restrict__ x, const float* __restrict__ theta,
    const float* __restrict__ head_w, const float* __restrict__ head_b,
    float* __restrict__ out)
{
  extern __shared__ __align__(16) char sbuf[];   // 2 x 69632 B state buffers
  __shared__ __align__(16) h16 Bm[24][256];      // B[n*16+k] per (d,p)
  __shared__ float2 gtab[DEPTH * NQ];            // (cos,sin) theta/2 at [d*14+bit]
  __shared__ float wT7[2][128];                  // head weights: v0-3->bits8-11, v4-6->bits5-7
  __shared__ float wRN[2][2][16];                // [o][0]: bits 0-3; [o][1]: b12,b13,b4
  __shared__ float xc[NQ], xs[NQ];               // input-encoding trig per bit
  __shared__ float redbuf[32];

  const int t = threadIdx.x;
  const int b = blockIdx.x;
  const int lane = t & 63;
  const int w = t >> 6;
  const int m = lane & 15;
  const int kg = lane >> 4;

  // ---- phase 0: small tables ----
  if (t < DEPTH * NQ) {
    int d = t / NQ, bit = t - d * NQ;
    float hg = 0.5f * theta[d * NQ + (13 - bit)];
    gtab[t] = make_float2(cosf(hg), sinf(hg));
  } else if (t >= 128 && t < 384) {
    int o = (t - 128) >> 7, v = (t - 128) & 127;
    float s = 0.f;
    #pragma unroll
    for (int i = 0; i < 4; ++i)
      s += ((v >> i) & 1) ? -head_w[o * NQ + 8 + i] : head_w[o * NQ + 8 + i];
    #pragma unroll
    for (int i = 0; i < 3; ++i)
      s += ((v >> (4 + i)) & 1) ? -head_w[o * NQ + 5 + i] : head_w[o * NQ + 5 + i];
    wT7[o][v] = s;
  } else if (t >= 384 && t < 448) {
    int u = t - 384, o = u >> 5, half = (u >> 4) & 1, idx = u & 15;
    float s;
    if (half == 0) {
      s = 0.f;
      #pragma unroll
      for (int i = 0; i < 4; ++i)
        s += ((idx >> i) & 1) ? -head_w[o * NQ + i] : head_w[o * NQ + i];
    } else {
      s  = (idx & 1) ? -head_w[o * NQ + 12] : head_w[o * NQ + 12];
      s += (idx & 2) ? -head_w[o * NQ + 13] : head_w[o * NQ + 13];
      s += (idx & 8) ? -head_w[o * NQ + 4]  : head_w[o * NQ + 4];
    }
    wRN[o][half][idx] = s;
  } else if (t >= 448 && t < 448 + NQ) {
    int bit = t - 448;
    float h = 0.5f * x[b * NQ + (13 - bit)];
    xc[bit] = cosf(h); xs[bit] = sinf(h);
  }
  __syncthreads();

  // ---- phase 1a: B matrices (identical arithmetic to round 5) ----
  #pragma unroll
  for (int i = 0; i < 6; ++i) {
    int e = t + (i << 10);
    int pid = e >> 8, n = (e >> 4) & 15, k = e & 15;
    int d = pid >> 2, p = pid & 3;
    float val;
    if (p < 3) {
      val = 1.f;
      #pragma unroll
      for (int j = 0; j < 4; ++j) {
        float2 g = gtab[d * NQ + 4 * p + j];
        val *= ((n >> j) & 1) ? (((k >> j) & 1) ? g.x : g.y)
                              : (((k >> j) & 1) ? -g.y : g.x);
      }
      if (d >= 1) {
        int s = ((k & (k >> 1)) ^ ((k >> 1) & (k >> 2)) ^ ((k >> 2) & (k >> 3))) & 1;
        if (s) val = -val;
      }
    } else {
      if ((((n ^ k) >> 2) & 3) != 0) val = 0.f;
      else {
        float2 gA = gtab[d * NQ + 12], gB = gtab[d * NQ + 13];
        float f0 = (n & 1) ? ((k & 1) ? gA.x : gA.y) : ((k & 1) ? -gA.y : gA.x);
        float f1 = ((n >> 1) & 1) ? (((k >> 1) & 1) ? gB.x : gB.y)
                                  : (((k >> 1) & 1) ? -gB.y : gB.x);
        val = f0 * f1;
        if (d >= 1 && (k & (k >> 1) & 1)) val = -val;
      }
    }
    Bm[pid][n * 16 + k] = (h16)val;
  }

  // ---- phase 1b: initial product state -> buf0 (view 0, E0=[12,13,c,8..11]) ----
  {
    int comp = t >> 9;
    int khi = t & 511;                       // k bits 5..13
    float mhi = 1.f;
    #pragma unroll
    for (int p2 = 5; p2 < 14; ++p2)
      mhi *= ((khi >> (p2 - 5)) & 1) ? xs[p2] : xc[p2];
    int pchi = __popc(khi);
    uint32_t T0 = ((khi >> 7) & 1) | (((khi >> 8) & 1) << 1)
                | ((uint32_t)comp << 2) | (((khi >> 3) & 15) << 3);
    uint32_t base = T0 * TS + ((uint32_t)(khi & 7) << 6);   // R bits 1-3
    #pragma unroll
    for (int blk = 0; blk < 4; ++blk) {
      union { h16 h[8]; uint4 u; } pk;
      #pragma unroll
      for (int i = 0; i < 8; ++i) {
        int j = blk * 8 + i;
        float mm = mhi;
        #pragma unroll
        for (int p2 = 0; p2 < 5; ++p2)
          mm *= ((j >> p2) & 1) ? xs[p2] : xc[p2];
        int e = (pchi + __popc(j)) & 3;       // (-i)^e
        float v = (comp == 0) ? ((e == 0) ? mm : ((e == 2) ? -mm : 0.f))
                              : ((e == 1) ? -mm : ((e == 3) ? mm : 0.f));
        pk.h[i] = (h16)v;
      }
      *(uint4*)(sbuf + base + (uint32_t)blk * 16) = pk.u;
    }
  }
  __syncthreads();

  char* buf0 = sbuf;
  char* buf1 = sbuf + 69632;
  float l0 = 0.f, l1 = 0.f;

  auto pass = [&](auto pc, const char* src, char* dst, int d, bool last) {
    constexpr int P = decltype(pc)::value;
    const h16* Bp = &Bm[d * 4 + P][0];
    h8 bv = {};
    if (kg < 2) bv = *(const h8*)(Bp + (m << 4) + (kg << 3));
    if (d >= 1 && P < 3 && (lane & 1) && kg == 1) {   // CZ cross-pair sign
      union { h8 v; uint4 u; } f; f.v = bv;
      f.u.x ^= 0x80008000u; f.u.y ^= 0x80008000u;
      f.u.z ^= 0x80008000u; f.u.w ^= 0x80008000u;
      bv = f.v;
    }
    // A-read base: (w*8+jt)*TS + m*32 + kg*16
    const uint32_t ra0 = (uint32_t)w * (8 * TS) + ((uint32_t)m << 5) + ((uint32_t)kg << 4);
    // C-write base/step into view p+1 (T'' low bits = m -> bank-minimal)
    uint32_t wb, wstep;
    if constexpr (P == 0 || P == 2) {
      wb = (uint32_t)m * TS + ((uint32_t)w << 5) + ((uint32_t)kg << 3);
      wstep = 16 * TS;
    } else if constexpr (P == 1) {
      wb = (uint32_t)(m >> 1) * TS + (uint32_t)(w & 1) * (64 * TS)
         + ((uint32_t)(w >> 1) << 5) + ((uint32_t)(m & 1) << 8) + ((uint32_t)kg << 3);
      wstep = 8 * TS;
    } else {
      wb = (uint32_t)(m & 7) * TS + (uint32_t)(w & 1) * (64 * TS)
         + ((uint32_t)(m >> 3) << 5) + ((uint32_t)(w >> 1) << 6) + ((uint32_t)kg << 3);
      wstep = 8 * TS;
    }
    float wn0 = 0.f, wn1 = 0.f;
    if (last) { wn0 = wRN[0][1][m]; wn1 = wRN[1][1][m]; }
    #pragma unroll
    for (int jt = 0; jt < 8; ++jt) {
      h8 av = {};
      if (kg < 2) av = *(const h8*)(src + ra0 + (uint32_t)jt * TS);
      f4 acc = {0.f, 0.f, 0.f, 0.f};
      acc = __builtin_amdgcn_mfma_f32_16x16x32_f16(av, bv, acc, 0, 0, 0);
      if (!last) {
        union { h16 h[4]; uint2 u; } pk;
        pk.h[0] = (h16)acc[0]; pk.h[1] = (h16)acc[1];
        pk.h[2] = (h16)acc[2]; pk.h[3] = (h16)acc[3];
        *(uint2*)(dst + wb + (uint32_t)jt * wstep) = pk.u;
      } else {
        int T = w * 8 + jt;   // E3: bits 8-11 (low), bits 5-7 (high)
        float wt0 = wT7[0][T], wt1 = wT7[1][T];
        #pragma unroll
        for (int j = 0; j < 4; ++j) {
          float pr = acc[j] * acc[j];
          int rp = kg * 4 + j;
          l0 += pr * (wt0 + wRN[0][0][rp] + wn0);
          l1 += pr * (wt1 + wRN[1][0][rp] + wn1);
        }
      }
    }
  };

  for (int d = 0; d < DEPTH; ++d) {
    pass(IC<0>{}, buf0, buf1, d, false); __syncthreads();
    pass(IC<1>{}, buf1, buf0, d, false); __syncthreads();
    pass(IC<2>{}, buf0, buf1, d, false); __syncthreads();
    bool last = (d == DEPTH - 1);
    pass(IC<3>{}, buf1, buf0, d, last);
    if (!last) __syncthreads();
  }

  #pragma unroll
  for (int off = 32; off > 0; off >>= 1) {
    l0 += __shfl_xor(l0, off);
    l1 += __shfl_xor(l1, off);
  }
  if (lane == 0) { redbuf[w] = l0; redbuf[16 + w] = l1; }
  __syncthreads();
  if (t == 0) {
    float s0 = head_b[0], s1 = head_b[1];
    #pragma unroll
    for (int i = 0; i < 16; ++i) { s0 += redbuf[i]; s1 += redbuf[16 + i]; }
    out[b * 2 + 0] = s0;
    out[b * 2 + 1] = s1;
  }
}

extern "C" void kernel_launch(void* const* d_in, const int* in_sizes, int n_in,
                              void* d_out, int out_size, void* d_ws, size_t ws_size,
                              hipStream_t stream) {
    const float* x      = (const float*)d_in[0];
    const float* theta  = (const float*)d_in[1];
    const float* head_w = (const float*)d_in[2];
    const float* head_b = (const float*)d_in[3];
    float* outp = (float*)d_out;
    const int batch = in_sizes[0] / NQ;  // 512
    qsim_kernel<<<batch, BLOCK, 2 * 69632, stream>>>(x, theta, head_w, head_b, outp);
}